// Round 4
// baseline (150.980 us; speedup 1.0000x reference)
//
#include <hip/hip_runtime.h>
#include <math.h>

// Problem constants (fixed by setup_inputs)
#define BB   16
#define HW   65536          // 256*256
#define NPIX (BB * HW)      // 1,048,576
#define PBLK 1024           // blocks in per-pixel kernels (4 pixels/thread, 256 thr)
#define CAP  2048           // per-image candidate-list capacity (bucket holds ~100-300)

// ws layout (bytes)
#define HIST1_OFF 0ull                  // 16*65536*4 = 4 MB
#define LCNT_OFF  (4ull << 20)          // 16 u32 (memset together with hist1)
#define G_OFF     ((4ull << 20) + 4096) // 16*256 u32 group sums (written, no memset)
#define LIST_OFF  ((4ull << 20) + (64ull << 10)) // 16*CAP u32 = 128 KB
#define UARR_OFF  (8ull << 20)          // 4 MB
#define CLSL_OFF  (12ull << 20)         // 4 MB
// 9 partial arrays of PBLK floats (plain stores, no contended atomics):
//  0: pos count  1: neg count  2..5: s1,m1,s0,m0  6: sum(clsl*clsw)
//  7: sel count (kB)  8: sum(clsl over selected) (kB)
#define PART_OFF  (16ull << 20)
#define STATS_OFF ((16ull << 20) + (64ull << 10))

// stats indices (u32 view unless noted) — every slot written, never accumulated
#define S_NPOS   0    // [16]
#define S_NNEG   16   // [16]
#define S_BUCKET 32   // [16] hi-16 bucket (0xFFFFFFFF = shortcut/skip)
#define S_RANK   48   // [16] 1-based rank within bucket
#define S_THR    64   // [16] select: u <= thr
#define F_S1     80   // float: s1,m1,s0,m0,wcl  (= part slots 2..6 reduced)
#define F_WCL    84

// monotone unsigned mapping of float bits (ascending float -> ascending uint)
__device__ __forceinline__ unsigned fmap(float x) {
  unsigned b = __float_as_uint(x);
  return (b & 0x80000000u) ? ~b : (b | 0x80000000u);
}

// log(1 + e^{-|d|}) with native exp/log: arg of log is in (1,2] -> accurate
__device__ __forceinline__ float softplus_neg_abs(float d) {
  return __logf(1.f + __expf(-fabsf(d)));
}

// Pass A: read both inputs once (16B loads, 4 pixels/thread).
// __launch_bounds__(256,4): VGPR cap 128 so all 20 float4 loads issue before
// the first waitcnt (at 48 VGPRs the compiler serialized them -> 1.2 TB/s).
__global__ __launch_bounds__(256, 4) void kA(
    const float* __restrict__ target, const float* __restrict__ logits,
    unsigned* __restrict__ hist1, unsigned* __restrict__ uarr,
    float* __restrict__ clsl, float* __restrict__ part) {
  int tid = blockIdx.x * 256 + threadIdx.x;
  int p0 = tid * 4;                 // 4 consecutive pixels, same image
  int b = p0 >> 16;
  int hw = p0 & 65535;

  const float4* t4 = (const float4*)(target + (size_t)p0 * 10);
  const float* lg = logits + (size_t)b * 10 * HW + hw;
  float4 T[10], L[10];
#pragma unroll
  for (int j = 0; j < 10; j++) T[j] = t4[j];
#pragma unroll
  for (int c = 0; c < 10; c++) L[c] = *(const float4*)(lg + (size_t)c * HW);

  float tf[40], lf[40];
#pragma unroll
  for (int j = 0; j < 10; j++) {
    tf[4 * j] = T[j].x; tf[4 * j + 1] = T[j].y; tf[4 * j + 2] = T[j].z; tf[4 * j + 3] = T[j].w;
    lf[4 * j] = L[j].x; lf[4 * j + 1] = L[j].y; lf[4 * j + 2] = L[j].z; lf[4 * j + 3] = L[j].w;
  }

  float cpos = 0.f, cneg = 0.f, s1 = 0.f, m1 = 0.f, s0 = 0.f, m0 = 0.f, wcl = 0.f;
  float cl4[4];
  unsigned uu[4];
#pragma unroll
  for (int q = 0; q < 4; q++) {
    float label = tf[10 * q];
    float wgt   = tf[10 * q + 1];
    bool pos = label > 0.f;
    bool neg = label == 0.f;
    float l0 = lf[0 * 4 + q], l1 = lf[1 * 4 + q];
    float d = l0 - l1;
    float cl = fmaxf(l0, l1) + softplus_neg_abs(d) - (pos ? l1 : l0);
    cl4[q] = cl;
    wcl += cl * wgt;
    cpos += pos ? 1.f : 0.f;
    cneg += neg ? 1.f : 0.f;
    unsigned u = fmap(d);           // score = sigmoid(d) monotone in d
    uu[q] = neg ? u : 0xFFFFFFFFu;  // finite d never maps to 0xFFFFFFFF
    if (neg) atomicAdd(&hist1[(size_t)b * 65536 + (u >> 16)], 1u);
#pragma unroll
    for (int n = 0; n < 4; n++) {
      float a = lf[(2 + n) * 4 + q];   // class-0 logit
      float c = lf[(6 + n) * 4 + q];   // class-1 logit
      float ce0 = fmaxf(a, c) + softplus_neg_abs(a - c);
      int lab = (int)tf[10 * q + 2 + n];
      float ce = ce0 - (lab ? c : a);
      float w = tf[10 * q + 6 + n];
      if (lab) { m1 += w; s1 += w * ce; }
      else     { m0 += w; s0 += w * ce; }
    }
  }
  *(float4*)(clsl + p0) = make_float4(cl4[0], cl4[1], cl4[2], cl4[3]);
  *(uint4*)(uarr + p0)  = make_uint4(uu[0], uu[1], uu[2], uu[3]);

  float vals[7] = {cpos, cneg, s1, m1, s0, m0, wcl};
  __shared__ float red[7][4];
  int lane = threadIdx.x & 63, wave = threadIdx.x >> 6;
#pragma unroll
  for (int q = 0; q < 7; q++) {
    float x = vals[q];
    for (int o = 32; o; o >>= 1) x += __shfl_down(x, o, 64);
    if (lane == 0) red[q][wave] = x;
  }
  __syncthreads();
  if (threadIdx.x < 7) {
    int q = threadIdx.x;
    part[(size_t)q * PBLK + blockIdx.x] = red[q][0] + red[q][1] + red[q][2] + red[q][3];
  }
}

// kG: blocks 0..255 -> hist1 group sums G[b][256] (256 bins/group), parallel.
//     blocks 256..271 -> per-image npos/nneg. blocks 272..276 -> link/wcl sums.
__global__ void kG(const unsigned* __restrict__ hist1, const float* __restrict__ part,
                   unsigned* __restrict__ G, unsigned* __restrict__ stats) {
  __shared__ unsigned ls[256];
  __shared__ float fr[4];
  int blk = blockIdx.x;
  int lane = threadIdx.x & 63, wave = threadIdx.x >> 6;
  if (blk < 256) {
    int b = blk >> 4, c = blk & 15;
    const unsigned* h = hist1 + (size_t)b * 65536 + (size_t)c * 4096 + (size_t)threadIdx.x * 16;
    unsigned s = 0;
#pragma unroll
    for (int j = 0; j < 16; j++) s += h[j];
    ls[threadIdx.x] = s;
    __syncthreads();
    if (threadIdx.x < 16) {
      unsigned g = 0;
#pragma unroll
      for (int j = 0; j < 16; j++) g += ls[threadIdx.x * 16 + j];
      G[b * 256 + c * 16 + threadIdx.x] = g;
    }
    return;
  }
  if (blk < 272) {
    int b = blk - 256;
    float cp = 0.f, cn = 0.f;
    if (threadIdx.x < 64) {
      cp = part[0 * PBLK + b * 64 + threadIdx.x];
      cn = part[1 * PBLK + b * 64 + threadIdx.x];
    }
    if (wave == 0) {
      for (int o = 32; o; o >>= 1) { cp += __shfl_down(cp, o, 64); cn += __shfl_down(cn, o, 64); }
      if (lane == 0) {
        stats[S_NPOS + b] = (unsigned)(cp + 0.5f);
        stats[S_NNEG + b] = (unsigned)(cn + 0.5f);
      }
    }
    return;
  }
  int q = blk - 272;                       // part slot 2+q -> stats F_S1+q
  const float* p = part + (size_t)(2 + q) * PBLK;
  float s = 0.f;
  for (int t = threadIdx.x; t < PBLK; t += 256) s += p[t];
  for (int o = 32; o; o >>= 1) s += __shfl_down(s, o, 64);
  if (lane == 0) fr[wave] = s;
  __syncthreads();
  if (threadIdx.x == 0) ((float*)stats)[F_S1 + q] = fr[0] + fr[1] + fr[2] + fr[3];
}

// kScan1: per image, find hi-16 bucket containing rank k. Reads G (256 u32)
// then one 256-bin group of hist1. shfl-based prefix, 2 KB total per image.
__global__ void kScan1(const unsigned* __restrict__ hist1, const unsigned* __restrict__ G,
                       unsigned* __restrict__ stats) {
  int b = blockIdx.x;
  int lane = threadIdx.x & 63, wave = threadIdx.x >> 6;
  unsigned npos = stats[S_NPOS + b], nneg = stats[S_NNEG + b];
  unsigned k = min(3u * npos, nneg);
  if (npos == 0u || k == 0u || k >= nneg) {
    // use_all OR k==n_neg: select all negatives (non-neg pixels carry 0xFFFFFFFF)
    if (threadIdx.x == 0) { stats[S_THR + b] = 0xFFFFFFFEu; stats[S_BUCKET + b] = 0xFFFFFFFFu; }
    return;
  }
  __shared__ unsigned wt[4];
  __shared__ unsigned s_g, s_rank;
  // --- stage 1: crossing group among 256 group sums ---
  unsigned cnt = G[b * 256 + threadIdx.x];
  unsigned x = cnt;
  for (int o = 1; o < 64; o <<= 1) { unsigned v = __shfl_up(x, o, 64); if (lane >= o) x += v; }
  if (lane == 63) wt[wave] = x;
  __syncthreads();
  unsigned woff = 0;
  for (int w = 0; w < wave; w++) woff += wt[w];
  unsigned incl = x + woff, excl = incl - cnt;
  if (excl < k && k <= incl) { s_g = (unsigned)threadIdx.x; s_rank = k - excl; }
  __syncthreads();
  unsigned g = s_g, rk = s_rank;
  __syncthreads();                       // protect wt before reuse
  // --- stage 2: crossing bin within group g ---
  unsigned cnt2 = hist1[(size_t)b * 65536 + (size_t)g * 256 + threadIdx.x];
  unsigned x2 = cnt2;
  for (int o = 1; o < 64; o <<= 1) { unsigned v = __shfl_up(x2, o, 64); if (lane >= o) x2 += v; }
  if (lane == 63) wt[wave] = x2;
  __syncthreads();
  unsigned woff2 = 0;
  for (int w = 0; w < wave; w++) woff2 += wt[w];
  unsigned incl2 = x2 + woff2, excl2 = incl2 - cnt2;
  if (excl2 < rk && rk <= incl2) {
    stats[S_BUCKET + b] = g * 256u + (unsigned)threadIdx.x;
    stats[S_RANK + b] = rk - excl2;
  }
}

// kD: compact u-values in the chosen bucket into a per-image list.
// Wave-aggregated list append (one u32 atomic per wave that has matches).
__global__ void kD(const unsigned* __restrict__ uarr, const unsigned* __restrict__ stats,
                   unsigned* __restrict__ lcnt, unsigned* __restrict__ list) {
  int b = blockIdx.x >> 6;                       // 64 blocks per image
  unsigned bk = stats[S_BUCKET + b];
  if (bk == 0xFFFFFFFFu) return;
  int p0 = (blockIdx.x * 256 + threadIdx.x) * 4;
  uint4 u4 = *(const uint4*)(uarr + p0);
  unsigned us[4] = {u4.x, u4.y, u4.z, u4.w};
  int lane = threadIdx.x & 63;
  unsigned long long below = (1ull << lane) - 1ull;
  unsigned total = 0, offs[4];
  bool m[4];
#pragma unroll
  for (int q = 0; q < 4; q++) {
    bool match = (us[q] >> 16) == bk;            // sentinel hi16=0xFFFF never matches real bucket
    m[q] = match;
    unsigned long long mk = __ballot(match);
    offs[q] = total + (unsigned)__popcll(mk & below);
    total += (unsigned)__popcll(mk);
  }
  if (total) {                                   // total is wave-uniform
    unsigned base = 0;
    if (lane == 0) base = atomicAdd(&lcnt[b], total);
    base = __shfl(base, 0, 64);
#pragma unroll
    for (int q = 0; q < 4; q++)
      if (m[q]) {
        unsigned idx = base + offs[q];
        if (idx < CAP) list[b * CAP + idx] = us[q];
      }
  }
}

// kSel: exact rank-th smallest within the candidate list (LDS brute force).
__global__ void kSel(const unsigned* __restrict__ list, const unsigned* __restrict__ lcnt,
                     unsigned* __restrict__ stats) {
  int b = blockIdx.x;
  unsigned bucket = stats[S_BUCKET + b];
  if (bucket == 0xFFFFFFFFu) return;
  unsigned n = min(lcnt[b], (unsigned)CAP);
  unsigned k = stats[S_RANK + b];                // 1-based, 1 <= k <= n
  __shared__ unsigned ls[CAP];
  for (unsigned t = threadIdx.x; t < n; t += 256) ls[t] = list[b * CAP + t];
  __syncthreads();
  if (n == 0) { if (threadIdx.x == 0) stats[S_THR + b] = bucket << 16; return; }
  for (unsigned ci = threadIdx.x; ci < n; ci += 256) {
    unsigned v = ls[ci];
    unsigned lt = 0, le = 0;
    for (unsigned j = 0; j < n; j++) { unsigned w = ls[j]; lt += (w < v); le += (w <= v); }
    if (lt < k && k <= le) stats[S_THR + b] = v;  // unique by value
  }
}

// Final per-pixel pass: selection; per-block partial stores (count + sum clsl).
__global__ void kB(const unsigned* __restrict__ uarr, const float* __restrict__ clsl,
                   const unsigned* __restrict__ stats, float* __restrict__ part) {
  int tid = blockIdx.x * 256 + threadIdx.x;
  int p0 = tid * 4;
  int b = p0 >> 16;
  unsigned thr = stats[S_THR + b];
  uint4 u4 = *(const uint4*)(uarr + p0);
  float4 c4 = *(const float4*)(clsl + p0);
  float cnt = 0.f, sum = 0.f;
  if (u4.x <= thr) { cnt += 1.f; sum += c4.x; }
  if (u4.y <= thr) { cnt += 1.f; sum += c4.y; }
  if (u4.z <= thr) { cnt += 1.f; sum += c4.z; }
  if (u4.w <= thr) { cnt += 1.f; sum += c4.w; }
  for (int o = 32; o; o >>= 1) {
    cnt += __shfl_down(cnt, o, 64);
    sum += __shfl_down(sum, o, 64);
  }
  __shared__ float rc[4], rs[4];
  int lane = threadIdx.x & 63, wave = threadIdx.x >> 6;
  if (lane == 0) { rc[wave] = cnt; rs[wave] = sum; }
  __syncthreads();
  if (threadIdx.x == 0) {
    part[7 * PBLK + blockIdx.x] = rc[0] + rc[1] + rc[2] + rc[3];
    part[8 * PBLK + blockIdx.x] = rs[0] + rs[1] + rs[2] + rs[3];
  }
}

// Reduce kB's partials + assemble both outputs. One block.
__global__ void kFinal(const float* __restrict__ part, const unsigned* __restrict__ stats,
                       float* __restrict__ out) {
  float cnt = 0.f, sum = 0.f;
  for (int t = threadIdx.x; t < PBLK; t += 256) {
    cnt += part[7 * PBLK + t];
    sum += part[8 * PBLK + t];
  }
  for (int o = 32; o; o >>= 1) {
    cnt += __shfl_down(cnt, o, 64);
    sum += __shfl_down(sum, o, 64);
  }
  __shared__ float rc[4], rs[4];
  int lane = threadIdx.x & 63, wave = threadIdx.x >> 6;
  if (lane == 0) { rc[wave] = cnt; rs[wave] = sum; }
  __syncthreads();
  if (threadIdx.x == 0) {
    unsigned nsel = (unsigned)(rc[0] + rc[1] + rc[2] + rc[3] + 0.5f);
    float selsum = rs[0] + rs[1] + rs[2] + rs[3];
    unsigned npos = 0;
    for (int b = 0; b < BB; b++) npos += stats[S_NPOS + b];
    const float* f = (const float*)stats;
    out[0] = 2.f * (f[F_WCL] + selsum) / (float)(npos + nsel);
    out[1] = (npos != 0u) ? (f[F_S1 + 0] / f[F_S1 + 1] + f[F_S1 + 2] / f[F_S1 + 3]) : 0.f;
  }
}

extern "C" void kernel_launch(void* const* d_in, const int* in_sizes, int n_in,
                              void* d_out, int out_size, void* d_ws, size_t ws_size,
                              hipStream_t stream) {
  const float* target = (const float*)d_in[0];   // (16,256,256,10)
  const float* logits = (const float*)d_in[1];   // (16,10,256,256)
  float* out = (float*)d_out;                    // [cls_loss*2, link_loss]
  char* ws = (char*)d_ws;

  unsigned* hist1 = (unsigned*)(ws + HIST1_OFF);
  unsigned* lcnt  = (unsigned*)(ws + LCNT_OFF);
  unsigned* G     = (unsigned*)(ws + G_OFF);
  unsigned* list  = (unsigned*)(ws + LIST_OFF);
  unsigned* uarr  = (unsigned*)(ws + UARR_OFF);
  float*    clsl  = (float*)(ws + CLSL_OFF);
  float*    part  = (float*)(ws + PART_OFF);
  unsigned* stats = (unsigned*)(ws + STATS_OFF);

  // hist1 + lcnt accumulate via atomics -> zero them (one contiguous memset).
  hipMemsetAsync(hist1, 0, (4ull << 20) + 64, stream);

  dim3 grid(PBLK), block(256);
  kA<<<grid, block, 0, stream>>>(target, logits, hist1, uarr, clsl, part);
  kG<<<277, 256, 0, stream>>>(hist1, part, G, stats);
  kScan1<<<BB, 256, 0, stream>>>(hist1, G, stats);
  kD<<<grid, block, 0, stream>>>(uarr, stats, lcnt, list);
  kSel<<<BB, 256, 0, stream>>>(list, lcnt, stats);
  kB<<<grid, block, 0, stream>>>(uarr, clsl, stats, part);
  kFinal<<<1, 256, 0, stream>>>(part, stats, out);
}